// Round 1
// baseline (1205.354 us; speedup 1.0000x reference)
//
#include <hip/hip_runtime.h>
#include <math.h>

#define NTOK 512
#define C    768
#define H    12
#define HD   64
#define NP   (NTOK*NTOK)   // 262144 pair rows
#define EPS  1e-5f

// workspace layout (float offsets)
#define OFF_GW   0u                               // 12*768 = 9216
#define OFF_SGW  9216u                            // 12
#define OFF_SBW  9232u                            // 12
#define OFF_BIAS 16384u                           // 12*512*512 = 3145728 (bias -> sim -> attn, in place)
#define OFF_XN   (OFF_BIAS + 3145728u)            // 512*768
#define OFF_QKV  (OFF_XN + 393216u)               // 512*2304
#define OFF_QN   (OFF_QKV + 1179648u)             // 512*768
#define OFF_KN   (OFF_QN + 393216u)               // 512*768
#define OFF_O    (OFF_KN + 393216u)               // 512*768

__device__ __forceinline__ float dot4(float4 a, float4 b){
    return a.x*b.x + a.y*b.y + a.z*b.z + a.w*b.w;
}

// ---------------- K0: gw = pn_g * w_bias, sgw = sum(pn_g*w), sbw = sum(pn_b*w)
__global__ void prep_gw_kernel(const float* __restrict__ pn_g, const float* __restrict__ pn_b,
                               const float* __restrict__ w_bias, float* __restrict__ ws){
    int h = blockIdx.x; int lane = threadIdx.x;
    float sg = 0.f, sb = 0.f;
    for (int c = lane; c < C; c += 64){
        float w  = w_bias[h*C + c];
        float gv = pn_g[c] * w;
        ws[OFF_GW + h*C + c] = gv;
        sg += gv;
        sb += pn_b[c] * w;
    }
    #pragma unroll
    for (int m = 32; m >= 1; m >>= 1){ sg += __shfl_xor(sg, m); sb += __shfl_xor(sb, m); }
    if (lane == 0){ ws[OFF_SGW + h] = sg; ws[OFF_SBW + h] = sb; }
}

// ---------------- K1: fused LN(pair) + einsum('bijc,hc->bhij')  (the 768 MB stream)
// block = 256 thr (4 waves). Each wave: 8 rows (16-lane group handles 2 rows). Block: 32 rows.
__global__ __launch_bounds__(256) void pair_bias_kernel(const float* __restrict__ pair,
                                                        const float* __restrict__ ws_in,
                                                        float* __restrict__ bias_out){
    __shared__ float gw[H*C];
    __shared__ float sgw[H], sbw[H];
    int tid = threadIdx.x;
    for (int idx = tid; idx < (H*C)/4; idx += 256)
        ((float4*)gw)[idx] = ((const float4*)(ws_in + OFF_GW))[idx];
    if (tid < H){ sgw[tid] = ws_in[OFF_SGW + tid]; sbw[tid] = ws_in[OFF_SBW + tid]; }
    __syncthreads();

    int w = tid >> 6, lane = tid & 63;
    int g = lane >> 4, q = lane & 15;
    int rbase = blockIdx.x * 32 + w * 8;
    int r0 = rbase + g, r1 = rbase + 4 + g;

    float s0 = 0.f, ss0 = 0.f, s1 = 0.f, ss1 = 0.f;
    float d0[H], d1[H];
    #pragma unroll
    for (int h = 0; h < H; h++){ d0[h] = 0.f; d1[h] = 0.f; }

    const float* p0base = pair + (size_t)r0 * C;
    const float* p1base = pair + (size_t)r1 * C;

    for (int ch = 0; ch < 12; ch++){
        int c0 = ch*64 + q*4;
        float4 gf[H];
        #pragma unroll
        for (int h = 0; h < H; h++) gf[h] = *(const float4*)&gw[h*C + c0];
        float4 p0 = *(const float4*)(p0base + c0);
        float4 p1 = *(const float4*)(p1base + c0);
        s0 += p0.x+p0.y+p0.z+p0.w;  ss0 += dot4(p0,p0);
        s1 += p1.x+p1.y+p1.z+p1.w;  ss1 += dot4(p1,p1);
        #pragma unroll
        for (int h = 0; h < H; h++){ d0[h] += dot4(p0, gf[h]); d1[h] += dot4(p1, gf[h]); }
    }
    // reduce within each 16-lane group
    #pragma unroll
    for (int m = 8; m >= 1; m >>= 1){
        s0 += __shfl_xor(s0,m); ss0 += __shfl_xor(ss0,m);
        s1 += __shfl_xor(s1,m); ss1 += __shfl_xor(ss1,m);
        #pragma unroll
        for (int h = 0; h < H; h++){ d0[h] += __shfl_xor(d0[h],m); d1[h] += __shfl_xor(d1[h],m); }
    }
    if (q == 0){
        float mu0 = s0*(1.f/C); float rs0 = 1.f/sqrtf(ss0*(1.f/C) - mu0*mu0 + EPS);
        float mu1 = s1*(1.f/C); float rs1 = 1.f/sqrtf(ss1*(1.f/C) - mu1*mu1 + EPS);
        #pragma unroll
        for (int h = 0; h < H; h++){
            bias_out[(size_t)h*NP + r0] = rs0*(d0[h] - mu0*sgw[h]) + sbw[h];
            bias_out[(size_t)h*NP + r1] = rs1*(d1[h] - mu1*sgw[h]) + sbw[h];
        }
    }
}

// ---------------- K2: generic row layernorm over 768, one wave per row, strided in/out
__global__ void rowln_kernel(const float* __restrict__ in, int in_stride,
                             float* __restrict__ out, int out_stride,
                             const float* __restrict__ g, const float* __restrict__ b){
    int row = blockIdx.x; int lane = threadIdx.x;
    const float* rp = in + (size_t)row * in_stride;
    float4 p[3];
    float s = 0.f, ss = 0.f;
    #pragma unroll
    for (int k = 0; k < 3; k++){
        p[k] = *(const float4*)(rp + k*256 + lane*4);
        s += p[k].x+p[k].y+p[k].z+p[k].w;  ss += dot4(p[k],p[k]);
    }
    #pragma unroll
    for (int m = 32; m >= 1; m >>= 1){ s += __shfl_xor(s,m); ss += __shfl_xor(ss,m); }
    float mu = s*(1.f/C);
    float rs = 1.f/sqrtf(ss*(1.f/C) - mu*mu + EPS);
    float* op = out + (size_t)row * out_stride;
    #pragma unroll
    for (int k = 0; k < 3; k++){
        int c = k*256 + lane*4;
        float4 gv = *(const float4*)(g + c);
        float4 bv = *(const float4*)(b + c);
        float4 r;
        r.x = (p[k].x - mu)*rs*gv.x + bv.x;
        r.y = (p[k].y - mu)*rs*gv.y + bv.y;
        r.z = (p[k].z - mu)*rs*gv.z + bv.z;
        r.w = (p[k].w - mu)*rs*gv.w + bv.w;
        *(float4*)(op + c) = r;
    }
}

// ---------------- K3/K7: fp32 tiled GEMM, O[M,N] = A[M,K] @ B[N,K]^T + bias[N]
// 64x64 tile, BK=16, 256 threads, 4x4 per thread
__global__ __launch_bounds__(256) void gemm_nt_kernel(const float* __restrict__ A, int lda,
                                                      const float* __restrict__ B, int ldb,
                                                      const float* __restrict__ bias,
                                                      float* __restrict__ Cc, int ldc, int K){
    __shared__ float As[16][64];
    __shared__ float Bs[16][64];
    int tid = threadIdx.x;
    int tx = tid & 15, ty = tid >> 4;
    int m0 = blockIdx.y * 64, n0 = blockIdx.x * 64;
    int lrow = tid >> 2, lkq = (tid & 3) * 4;
    float acc[4][4] = {};
    const float* ap = A + (size_t)(m0 + lrow)*lda + lkq;
    const float* bp = B + (size_t)(n0 + lrow)*ldb + lkq;
    for (int k0 = 0; k0 < K; k0 += 16){
        float4 av = *(const float4*)(ap + k0);
        float4 bv = *(const float4*)(bp + k0);
        __syncthreads();
        As[lkq+0][lrow] = av.x; As[lkq+1][lrow] = av.y; As[lkq+2][lrow] = av.z; As[lkq+3][lrow] = av.w;
        Bs[lkq+0][lrow] = bv.x; Bs[lkq+1][lrow] = bv.y; Bs[lkq+2][lrow] = bv.z; Bs[lkq+3][lrow] = bv.w;
        __syncthreads();
        #pragma unroll
        for (int k = 0; k < 16; k++){
            float4 a = *(float4*)&As[k][ty*4];
            float4 b = *(float4*)&Bs[k][tx*4];
            float ar[4] = {a.x,a.y,a.z,a.w};
            float br[4] = {b.x,b.y,b.z,b.w};
            #pragma unroll
            for (int i = 0; i < 4; i++)
                #pragma unroll
                for (int j = 0; j < 4; j++)
                    acc[i][j] += ar[i]*br[j];
        }
    }
    float4 bb = *(const float4*)(bias + n0 + tx*4);
    #pragma unroll
    for (int i = 0; i < 4; i++){
        float* orow = Cc + (size_t)(m0 + ty*4 + i)*ldc + n0 + tx*4;
        float4 r;
        r.x = acc[i][0] + bb.x; r.y = acc[i][1] + bb.y;
        r.z = acc[i][2] + bb.z; r.w = acc[i][3] + bb.w;
        *(float4*)orow = r;
    }
}

// ---------------- K5a: sim[h,i,j] = 0.125 * q_h[i].k_h[j] + bias[h,i,j]  (in place over bias)
__global__ __launch_bounds__(256) void qk_bias_kernel(const float* __restrict__ qn,
                                                      const float* __restrict__ kn,
                                                      float* __restrict__ attn){
    int h = blockIdx.z, i0 = blockIdx.y*32, j0 = blockIdx.x*64;
    __shared__ float4 Qs4[32*16];   // [i][d4]
    __shared__ float4 Ks4[16*64];   // [d4][j] -> conflict-free read by j=lane
    int tid = threadIdx.x;
    #pragma unroll
    for (int v = 0; v < 2; v++){
        int idx = tid + 256*v; int d4 = idx & 15, i = idx >> 4;
        Qs4[i*16 + d4] = *(const float4*)&qn[(size_t)(i0+i)*C + h*HD + d4*4];
    }
    #pragma unroll
    for (int v = 0; v < 4; v++){
        int idx = tid + 256*v; int d4 = idx & 15, j = idx >> 4;
        Ks4[d4*64 + j] = *(const float4*)&kn[(size_t)(j0+j)*C + h*HD + d4*4];
    }
    __syncthreads();
    int jl = tid & 63, w = tid >> 6;
    float acc[8] = {};
    #pragma unroll
    for (int d4 = 0; d4 < 16; d4++){
        float4 kv = Ks4[d4*64 + jl];
        #pragma unroll
        for (int r = 0; r < 8; r++)
            acc[r] += dot4(Qs4[(w*8+r)*16 + d4], kv);
    }
    #pragma unroll
    for (int r = 0; r < 8; r++){
        int i = i0 + w*8 + r;
        size_t off = (size_t)h*NP + (size_t)i*NTOK + j0 + jl;
        attn[off] = acc[r]*0.125f + attn[off];
    }
}

// ---------------- K5b: row softmax over 512, one wave per (h,i)
__global__ void softmax_kernel(float* __restrict__ attn){
    size_t base = (size_t)blockIdx.x * NTOK;
    int lane = threadIdx.x;
    float4* row4 = (float4*)(attn + base);
    float4 v0 = row4[lane], v1 = row4[lane + 64];
    float m = fmaxf(fmaxf(fmaxf(v0.x,v0.y),fmaxf(v0.z,v0.w)),
                    fmaxf(fmaxf(v1.x,v1.y),fmaxf(v1.z,v1.w)));
    #pragma unroll
    for (int s = 32; s >= 1; s >>= 1) m = fmaxf(m, __shfl_xor(m, s));
    v0.x = __expf(v0.x - m); v0.y = __expf(v0.y - m); v0.z = __expf(v0.z - m); v0.w = __expf(v0.w - m);
    v1.x = __expf(v1.x - m); v1.y = __expf(v1.y - m); v1.z = __expf(v1.z - m); v1.w = __expf(v1.w - m);
    float sum = v0.x+v0.y+v0.z+v0.w + v1.x+v1.y+v1.z+v1.w;
    #pragma unroll
    for (int s = 32; s >= 1; s >>= 1) sum += __shfl_xor(sum, s);
    float inv = 1.f/sum;
    v0.x *= inv; v0.y *= inv; v0.z *= inv; v0.w *= inv;
    v1.x *= inv; v1.y *= inv; v1.z *= inv; v1.w *= inv;
    row4[lane] = v0; row4[lane + 64] = v1;
}

// ---------------- K6: o[i, h*64+d] = sum_j attn[h,i,j] * v[j, h*64+d]   (v lives inside qkv)
__global__ __launch_bounds__(256) void av_kernel(const float* __restrict__ attn,
                                                 const float* __restrict__ qkv,
                                                 float* __restrict__ o){
    int h = blockIdx.y, i0 = blockIdx.x*32;
    __shared__ float  As[32*64];    // [i][j]
    __shared__ float4 Vs4[64*16];   // [j][d4] -> conflict-free read by d4=lane
    int tid = threadIdx.x;
    int d4 = tid & 15, ig = tid >> 4;
    float4 acc0 = {0,0,0,0}, acc1 = {0,0,0,0};
    for (int jt = 0; jt < 8; jt++){
        int j0 = jt*64;
        __syncthreads();
        #pragma unroll
        for (int v = 0; v < 2; v++){
            int idx = tid + 256*v; int jq = idx & 15, i = idx >> 4;
            *(float4*)&As[i*64 + jq*4] =
                *(const float4*)&attn[(size_t)h*NP + (size_t)(i0+i)*NTOK + j0 + jq*4];
        }
        #pragma unroll
        for (int v = 0; v < 4; v++){
            int idx = tid + 256*v; int dd = idx & 15, j = idx >> 4;
            Vs4[j*16 + dd] = *(const float4*)&qkv[(size_t)(j0+j)*(3*C) + 2*C + h*HD + dd*4];
        }
        __syncthreads();
        #pragma unroll
        for (int j = 0; j < 64; j++){
            float4 vv = Vs4[j*16 + d4];
            float a0 = As[(ig*2)*64 + j];
            float a1 = As[(ig*2+1)*64 + j];
            acc0.x += a0*vv.x; acc0.y += a0*vv.y; acc0.z += a0*vv.z; acc0.w += a0*vv.w;
            acc1.x += a1*vv.x; acc1.y += a1*vv.y; acc1.z += a1*vv.z; acc1.w += a1*vv.w;
        }
    }
    int i = i0 + ig*2;
    *(float4*)&o[(size_t)i*C + h*HD + d4*4]     = acc0;
    *(float4*)&o[(size_t)(i+1)*C + h*HD + d4*4] = acc1;
}

extern "C" void kernel_launch(void* const* d_in, const int* in_sizes, int n_in,
                              void* d_out, int out_size, void* d_ws, size_t ws_size,
                              hipStream_t stream){
    const float* x      = (const float*)d_in[0];
    const float* pair   = (const float*)d_in[1];
    const float* ln_g   = (const float*)d_in[2];
    const float* ln_b   = (const float*)d_in[3];
    const float* w_qkv  = (const float*)d_in[4];
    const float* b_qkv  = (const float*)d_in[5];
    const float* w_proj = (const float*)d_in[6];
    const float* b_proj = (const float*)d_in[7];
    const float* w_bias = (const float*)d_in[8];
    const float* pn_g   = (const float*)d_in[9];
    const float* pn_b   = (const float*)d_in[10];
    const float* qln_g  = (const float*)d_in[11];
    const float* qln_b  = (const float*)d_in[12];
    const float* kln_g  = (const float*)d_in[13];
    const float* kln_b  = (const float*)d_in[14];
    float* ws  = (float*)d_ws;
    float* out = (float*)d_out;

    prep_gw_kernel<<<H, 64, 0, stream>>>(pn_g, pn_b, w_bias, ws);
    pair_bias_kernel<<<NP/32, 256, 0, stream>>>(pair, ws, ws + OFF_BIAS);
    rowln_kernel<<<NTOK, 64, 0, stream>>>(x, C, ws + OFF_XN, C, ln_g, ln_b);
    gemm_nt_kernel<<<dim3(3*C/64, NTOK/64), 256, 0, stream>>>(
        ws + OFF_XN, C, w_qkv, C, b_qkv, ws + OFF_QKV, 3*C, C);
    rowln_kernel<<<NTOK, 64, 0, stream>>>(ws + OFF_QKV,     3*C, ws + OFF_QN, C, qln_g, qln_b);
    rowln_kernel<<<NTOK, 64, 0, stream>>>(ws + OFF_QKV + C, 3*C, ws + OFF_KN, C, kln_g, kln_b);
    qk_bias_kernel<<<dim3(NTOK/64, NTOK/32, H), 256, 0, stream>>>(
        ws + OFF_QN, ws + OFF_KN, ws + OFF_BIAS);
    softmax_kernel<<<H*NTOK, 64, 0, stream>>>(ws + OFF_BIAS);
    av_kernel<<<dim3(NTOK/32, H), 256, 0, stream>>>(ws + OFF_BIAS, ws + OFF_QKV, ws + OFF_O);
    gemm_nt_kernel<<<dim3(C/64, NTOK/64), 256, 0, stream>>>(
        ws + OFF_O, C, w_proj, C, b_proj, out, C, C);
}